// Round 5
// baseline (65.634 us; speedup 1.0000x reference)
//
#include <hip/hip_runtime.h>

// Batched zero-phase Butterworth filtfilt (order 5), rows of length 8192.
// One block (256 thr) per row; each thread owns a 32-sample output chunk.
// SINGLE-BARRIER design: after staging x into LDS (swizzled, conflict-free),
// every thread is self-sufficient:
//   forward : warm over chunk tid-1 (32 steps, pole decay 0.819^32~1.7e-3),
//             filter own chunk -> yreg, CONTINUE into chunk tid+1 -> ynx
//             (the thread computes the neighbor y it needs for the backward
//             warmup itself -- 64-step-warmed, better than an exchange).
//   backward: init zi*ynx[31], warm descending over ynx, then own chunk from
//             yreg (in place), float4 store.
// Edge paths (tid 0 forward, tid 255 tail+backward) follow the reference
// recursion exactly. No LDS writes after phase A, no y exchange, no barriers
// past the first -> waves run free; latency hidden by 16 waves/CU.

#define NN   8192
#define PADL 18
#define LC   32
#define TPB  256

// swizzled word index: element i of chunk c at word i*256 + (c ^ swz(i))
__device__ __forceinline__ int xw(int c, int i) {
    return (i << 8) + (c ^ (((i >> 2) & 7) << 2));
}

// one DF2T step; updates z0..z4, sets yv (10 fma + 1 mul)
#define STEP(xv) do {                               \
    float y_ = fmaf(b0, (xv), z0);                  \
    z0 = fmaf(na1, y_, fmaf(b1, (xv), z1));         \
    z1 = fmaf(na2, y_, fmaf(b2, (xv), z2));         \
    z2 = fmaf(na3, y_, fmaf(b3, (xv), z3));         \
    z3 = fmaf(na4, y_, fmaf(b4, (xv), z4));         \
    z4 = fmaf(na5, y_, b5 * (xv));                  \
    yv = y_;                                        \
} while (0)

__global__ __launch_bounds__(TPB, 4) void GREEN_62869731278967_filtfilt(
    const float* __restrict__ x,
    const float* __restrict__ bc,
    const float* __restrict__ ac,
    const float* __restrict__ zc,
    float* __restrict__ out)
{
    __shared__ float lds[NN];            // 32768 B exactly
    const int row = blockIdx.x;
    const int tid = threadIdx.x;
    const float* xr   = x   + (size_t)row * NN;
    float*       outr = out + (size_t)row * NN;

    const float b0 = bc[0], b1 = bc[1], b2 = bc[2], b3 = bc[3], b4 = bc[4], b5 = bc[5];
    const float na1 = -ac[1], na2 = -ac[2], na3 = -ac[3], na4 = -ac[4], na5 = -ac[5];
    const float zi0 = zc[0], zi1 = zc[1], zi2 = zc[2], zi3 = zc[3], zi4 = zc[4];

    // ---- Phase A: coalesced float4 loads -> swizzled LDS ----
    // j = 1024q + 4t + m  =>  word = 1024(t&7) + 256m + 32q + ((t>>3)^((t&7)<<2))
    {
        const int Abase = ((tid & 7) << 10) + ((tid >> 3) ^ ((tid & 7) << 2));
#pragma unroll
        for (int q = 0; q < 8; ++q) {
            float4 v = *reinterpret_cast<const float4*>(xr + (q << 10) + (tid << 2));
            lds[Abase + (q << 5) + 0]   = v.x;
            lds[Abase + (q << 5) + 256] = v.y;
            lds[Abase + (q << 5) + 512] = v.z;
            lds[Abase + (q << 5) + 768] = v.w;
        }
    }
    __syncthreads();   // the ONLY barrier; LDS is read-only from here on

    float yreg[LC];    // own forward y
    float ynx[LC];     // next chunk's forward y (tid<255) / 18-sample tail (tid 255)
    float z0, z1, z2, z3, z4, yv;

    // ---- forward ----
    if (tid == 0) {
        // exact reference path: init zi*ext[0], feed the 18 reflected samples
        const float x0 = lds[xw(0, 0)];
        float v0 = 2.f * x0 - lds[xw(0, PADL)];
        z0 = zi0 * v0; z1 = zi1 * v0; z2 = zi2 * v0; z3 = zi3 * v0; z4 = zi4 * v0;
#pragma unroll
        for (int t = 0; t < PADL; ++t) {
            float v = 2.f * x0 - lds[xw(0, PADL - t)];
            STEP(v);
        }
    } else {
        // approximate: init zi*x[first], warm over exactly chunk tid-1
        float v0 = lds[xw(tid - 1, 0)];
        z0 = zi0 * v0; z1 = zi1 * v0; z2 = zi2 * v0; z3 = zi3 * v0; z4 = zi4 * v0;
#pragma unroll
        for (int i = 0; i < LC; ++i) STEP(lds[xw(tid - 1, i)]);
    }
    // own chunk
#pragma unroll
    for (int i = 0; i < LC; ++i) { STEP(lds[xw(tid, i)]); yreg[i] = yv; }
    // continue into next chunk (or reflected tail for the last thread)
    if (tid < TPB - 1) {
#pragma unroll
        for (int i = 0; i < LC; ++i) { STEP(lds[xw(tid + 1, i)]); ynx[i] = yv; }
    } else {
        const float xN = lds[xw(TPB - 1, 31)];
#pragma unroll
        for (int i = 0; i < PADL; ++i) {
            float v = 2.f * xN - lds[xw(TPB - 1, 30 - i)];
            STEP(v);
            ynx[i] = yv;                 // ynx[i] = y[8210+i]
        }
    }

    // ---- backward ----
    if (tid == TPB - 1) {
        // exact reference path: init zi*y_last, feed 18 tail samples descending
        float u0 = ynx[PADL - 1];
        z0 = zi0 * u0; z1 = zi1 * u0; z2 = zi2 * u0; z3 = zi3 * u0; z4 = zi4 * u0;
#pragma unroll
        for (int s = 0; s < PADL; ++s) STEP(ynx[PADL - 1 - s]);
    } else {
        // approximate: init zi*ynx[31], warm descending over next chunk's y
        float u0 = ynx[LC - 1];
        z0 = zi0 * u0; z1 = zi1 * u0; z2 = zi2 * u0; z3 = zi3 * u0; z4 = zi4 * u0;
#pragma unroll
        for (int i = 0; i < LC; ++i) STEP(ynx[LC - 1 - i]);
    }
    // own chunk descending, in place
#pragma unroll
    for (int i = 0; i < LC; ++i) { STEP(yreg[LC - 1 - i]); yreg[LC - 1 - i] = yv; }

    // ---- store ----
#pragma unroll
    for (int q = 0; q < LC / 4; ++q) {
        float4 v;
        v.x = yreg[4 * q + 0];
        v.y = yreg[4 * q + 1];
        v.z = yreg[4 * q + 2];
        v.w = yreg[4 * q + 3];
        *reinterpret_cast<float4*>(outr + tid * LC + 4 * q) = v;
    }
}

extern "C" void kernel_launch(void* const* d_in, const int* in_sizes, int n_in,
                              void* d_out, int out_size, void* d_ws, size_t ws_size,
                              hipStream_t stream) {
    const float* x  = (const float*)d_in[0];
    const float* b  = (const float*)d_in[1];
    const float* a  = (const float*)d_in[2];
    const float* zi = (const float*)d_in[3];
    float* out = (float*)d_out;
    const int rows = in_sizes[0] / NN;   // 4096
    GREEN_62869731278967_filtfilt<<<rows, TPB, 0, stream>>>(x, b, a, zi, out);
}